// Round 8
// baseline (4710.703 us; speedup 1.0000x reference)
//
#include <hip/hip_runtime.h>
#include <cstdint>
#include <cstddef>

#define NBATCH  8
#define NPTS    8192
#define NFEAT   64
#define NPOINT  2048
#define NSAMPLE 32

// ---------------------------------------------------------------------------
// prep: fold BN into weights (y = dot*s + t), transpose to [c][o]
// ---------------------------------------------------------------------------
__global__ void prep_kernel(const float* __restrict__ w1, const float* __restrict__ b1,
                            const float* __restrict__ g1, const float* __restrict__ bb1,
                            const float* __restrict__ m1, const float* __restrict__ v1,
                            const float* __restrict__ w2, const float* __restrict__ b2,
                            const float* __restrict__ g2, const float* __restrict__ bb2,
                            const float* __restrict__ m2, const float* __restrict__ v2,
                            const float* __restrict__ w3, const float* __restrict__ b3,
                            const float* __restrict__ g3, const float* __restrict__ bb3,
                            const float* __restrict__ m3, const float* __restrict__ v3,
                            float* __restrict__ wbuf) {
    int i = blockIdx.x * 256 + threadIdx.x;
    if (i < 4288) {
        int o = i & 63, c = i >> 6;
        float s = g1[o] / sqrtf(v1[o] + 1e-5f);
        wbuf[i] = w1[o * 67 + c] * s;
    } else if (i < 4352) {
        int o = i - 4288;
        float s = g1[o] / sqrtf(v1[o] + 1e-5f);
        wbuf[i] = (b1[o] - m1[o]) * s + bb1[o];
    } else if (i < 8448) {
        int j = i - 4352; int o = j & 63, c = j >> 6;
        float s = g2[o] / sqrtf(v2[o] + 1e-5f);
        wbuf[i] = w2[o * 64 + c] * s;
    } else if (i < 8512) {
        int o = i - 8448;
        float s = g2[o] / sqrtf(v2[o] + 1e-5f);
        wbuf[i] = (b2[o] - m2[o]) * s + bb2[o];
    } else if (i < 16704) {
        int j = i - 8512; int o = j & 127, c = j >> 7;
        float s = g3[o] / sqrtf(v3[o] + 1e-5f);
        wbuf[i] = w3[o * 64 + c] * s;
    } else if (i < 16832) {
        int o = i - 16704;
        float s = g3[o] / sqrtf(v3[o] + 1e-5f);
        wbuf[i] = (b3[o] - m3[o]) * s + bb3[o];
    }
}

// ---------------------------------------------------------------------------
// FPS, latency-optimized brute force — no-spill shape.
// 512 threads (8 waves, 2/SIMD), 16 points/thread register-resident
// (R3-proven allocation: ~88-120 VGPR, no scratch). Index of slot j is
// tid + 512*j (computed). Per iteration:
//   - 16-point exact-IEEE dd update (numpy recipe, validated R1-R7);
//     thread-local argmax carries winning (v, idx, x, y, z).
//   - in-wave argmax via DPP (row_shr 1/2/4/8 + row_bcast15/31) carrying
//     all 5 values; lane 63 = wave winner (validated R7).
//   - cross-wave: 8 partials x 5 values in LDS (parity double-buffered),
//     ONE barrier, all threads serially scan 8 -> next centroid directly.
// Tie-break (v>, ==&&idx<) everywhere == numpy argmax. No LDS point table,
// no sort, no atomics, no indexed centroid fetch.
// ---------------------------------------------------------------------------
template <int CTRL>
__device__ __forceinline__ int dpp_mov(int x) {
    return __builtin_amdgcn_update_dpp(x, x, CTRL, 0xF, 0xF, false);
}

#define DPP_ARGMAX_STEP(CTRL)                                               \
    do {                                                                    \
        float vv = __int_as_float(dpp_mov<CTRL>(__float_as_int(v)));        \
        int   oo = dpp_mov<CTRL>(o);                                        \
        float xx = __int_as_float(dpp_mov<CTRL>(__float_as_int(wx)));       \
        float yy = __int_as_float(dpp_mov<CTRL>(__float_as_int(wy)));       \
        float zz = __int_as_float(dpp_mov<CTRL>(__float_as_int(wz)));       \
        bool tk = (vv > v) || (vv == v && oo < o);                          \
        v = tk ? vv : v; o = tk ? oo : o;                                   \
        wx = tk ? xx : wx; wy = tk ? yy : wy; wz = tk ? zz : wz;            \
    } while (0)

__global__ __launch_bounds__(512, 2) void fps_kernel(const float* __restrict__ points,
                                                     int* __restrict__ fidx) {
    const int b = blockIdx.x;
    const int tid = threadIdx.x;
    const int lane = tid & 63;
    const int wv = tid >> 6;
    const float* __restrict__ pxg = points + (size_t)b * 3 * NPTS;
    const float* __restrict__ pyg = pxg + NPTS;
    const float* __restrict__ pzg = pyg + NPTS;

    __shared__ float pvs[2][8], pxs[2][8], pys[2][8], pzs[2][8];
    __shared__ int   pos[2][8];

    float rx[16], ry[16], rz[16], rdd[16];
#pragma unroll
    for (int j = 0; j < 16; ++j) {
        int n = tid + 512 * j;
        rx[j] = pxg[n]; ry[j] = pyg[n]; rz[j] = pzg[n];
        rdd[j] = 1e10f;
    }
    // initial centroid = original point 0 (broadcast global loads, L2-hit)
    float cx = pxg[0], cy = pyg[0], cz = pzg[0];
    if (tid == 0) fidx[b * NPOINT] = 0;

    for (int i = 1; i < NPOINT; ++i) {
        // ---- 16-point register update + thread-local argmax (carry coords) ----
        float bv = -1.0f; int bj = 0;
        float bx = 0.f, by = 0.f, bz = 0.f;
#pragma unroll
        for (int j = 0; j < 16; ++j) {
            float dx = __fsub_rn(rx[j], cx);
            float dy = __fsub_rn(ry[j], cy);
            float dz = __fsub_rn(rz[j], cz);
            float d  = __fadd_rn(__fadd_rn(__fmul_rn(dx, dx), __fmul_rn(dy, dy)),
                                 __fmul_rn(dz, dz));
            float nd = fminf(rdd[j], d);
            rdd[j] = nd;
            bool take = (nd > bv);   // j ascending => smaller n wins ties locally
            bv = take ? nd : bv; bj = take ? j : bj;
            bx = take ? rx[j] : bx; by = take ? ry[j] : by; bz = take ? rz[j] : bz;
        }
        float v = bv; int o = tid + (bj << 9);
        float wx = bx, wy = by, wz = bz;
        // ---- in-wave argmax via DPP; lane 63 holds the wave winner ----
        DPP_ARGMAX_STEP(0x111);   // row_shr:1
        DPP_ARGMAX_STEP(0x112);   // row_shr:2
        DPP_ARGMAX_STEP(0x114);   // row_shr:4
        DPP_ARGMAX_STEP(0x118);   // row_shr:8
        DPP_ARGMAX_STEP(0x142);   // row_bcast15
        DPP_ARGMAX_STEP(0x143);   // row_bcast31
        const int par = i & 1;
        if (lane == 63) {
            pvs[par][wv] = v; pos[par][wv] = o;
            pxs[par][wv] = wx; pys[par][wv] = wy; pzs[par][wv] = wz;
        }
        __syncthreads();
        // ---- serial scan of 8 partials (broadcast LDS reads) ----
        float M = pvs[par][0]; int I = pos[par][0];
        float nx = pxs[par][0], ny = pys[par][0], nz = pzs[par][0];
#pragma unroll
        for (int k = 1; k < 8; ++k) {
            float vk = pvs[par][k]; int ok = pos[par][k];
            bool tk = (vk > M) || (vk == M && ok < I);
            M = tk ? vk : M; I = tk ? ok : I;
            nx = tk ? pxs[par][k] : nx; ny = tk ? pys[par][k] : ny; nz = tk ? pzs[par][k] : nz;
        }
        cx = nx; cy = ny; cz = nz;
        if (tid == 0) fidx[b * NPOINT + i] = I;
    }
}

// ---------------------------------------------------------------------------
// Ball query: one wave per query. d = (qq+pp) - 2*qp, compare vs 0.04f.
// qp is the K=3 einsum/dot -> ascending FMA chain (verified exact in R1).
// ---------------------------------------------------------------------------
__global__ __launch_bounds__(256) void bq_kernel(const float* __restrict__ points,
                                                 const int* __restrict__ fidx,
                                                 int* __restrict__ ballidx,
                                                 float* __restrict__ out_xyz) {
    const int lane = threadIdx.x & 63;
    const int gw = (blockIdx.x << 2) + (threadIdx.x >> 6);
    const int b = gw >> 11;
    const int q = gw & 2047;
    const float* __restrict__ pxg = points + (size_t)b * 3 * NPTS;
    const float* __restrict__ pyg = pxg + NPTS;
    const float* __restrict__ pzg = pyg + NPTS;
    const int qi = fidx[b * NPOINT + q];
    const float qx = pxg[qi], qy = pyg[qi], qz = pzg[qi];
    const float qq = __fadd_rn(__fadd_rn(__fmul_rn(qx, qx), __fmul_rn(qy, qy)),
                               __fmul_rn(qz, qz));
    int* __restrict__ out = ballidx + ((size_t)(b * NPOINT + q)) * NSAMPLE;
    int have = 0;
    int first = -1;
    for (int base = 0; base < NPTS && have < NSAMPLE; base += 64) {
        const int n = base + lane;
        float x = pxg[n], y = pyg[n], z = pzg[n];
        float pp = __fadd_rn(__fadd_rn(__fmul_rn(x, x), __fmul_rn(y, y)), __fmul_rn(z, z));
        float qp = __builtin_fmaf(qz, z, __builtin_fmaf(qy, y, __fmul_rn(qx, x)));
        float d  = __fsub_rn(__fadd_rn(qq, pp), __fmul_rn(2.0f, qp));
        bool inb = d < 0.04f;   // f32(0.2*0.2) == 0.04f
        unsigned long long mask = __ballot(inb);
        if (mask) {
            if (first < 0) first = base + __ffsll(mask) - 1;
            if (inb) {
                int slot = have + (int)__popcll(mask & ((1ull << lane) - 1ull));
                if (slot < NSAMPLE) out[slot] = n;
            }
            have += (int)__popcll(mask);
        }
    }
    for (int s = have + lane; s < NSAMPLE; s += 64) out[s] = first;
    if (lane == 0) {
        float* o0 = out_xyz + (size_t)b * 3 * NPOINT + q;
        o0[0] = qx; o0[NPOINT] = qy; o0[2 * NPOINT] = qz;
    }
}

// ---------------------------------------------------------------------------
// Fused gather + 3-layer MLP (BN folded) + max-pool. One query per block,
// 256 threads. LDS tiles with stride 36 (float4-aligned, writes only 8-way).
// ---------------------------------------------------------------------------
#define XS 36
__global__ __launch_bounds__(256) void mlp_kernel(const float* __restrict__ feats,
                                                  const float* __restrict__ points,
                                                  const int* __restrict__ fidx,
                                                  const int* __restrict__ ballidx,
                                                  const float* __restrict__ wbuf,
                                                  float* __restrict__ out) {
    __shared__ float xT[67 * XS];   // [c][k], also reused for y2
    __shared__ float yA[64 * XS];   // y1, also reused for final partial max
    __shared__ float wl[8192];      // current layer's folded weights [c][o]
    __shared__ float bl[128];
    __shared__ int   il[32];
    __shared__ float qv[3];
    const int tid = threadIdx.x;
    const int bq = blockIdx.x;
    const int b = bq >> 11, q = bq & 2047;
    const float* __restrict__ pb = points + (size_t)b * 3 * NPTS;

    if (tid < 32) il[tid] = ballidx[((size_t)(b * NPOINT + q)) * NSAMPLE + tid];
    if (tid < 3)  qv[tid] = pb[(size_t)tid * NPTS + fidx[b * NPOINT + q]];
    for (int i = tid; i < 4288; i += 256) wl[i] = wbuf[i];
    if (tid < 64) bl[tid] = wbuf[4288 + tid];
    __syncthreads();

    // build xT: rows 0..2 = grouped_xyz, rows 3..66 = gathered features
    if (tid < 32) {
        int n = il[tid];
        xT[0 * XS + tid] = pb[n] - qv[0];
        xT[1 * XS + tid] = pb[NPTS + n] - qv[1];
        xT[2 * XS + tid] = pb[2 * NPTS + n] - qv[2];
    }
    {
        int k = tid & 31, fg = tid >> 5;
        int n = il[k];
        const float* fb = feats + ((size_t)b * NFEAT + fg * 8) * NPTS + n;
#pragma unroll
        for (int u = 0; u < 8; ++u) xT[(3 + fg * 8 + u) * XS + k] = fb[(size_t)u * NPTS];
    }
    __syncthreads();

    const int o = tid & 63, kb = tid >> 6;
    float acc[8];
    // ---- layer 1: 67 -> 64 ----
#pragma unroll
    for (int j = 0; j < 8; ++j) acc[j] = 0.f;
    for (int c = 0; c < 67; ++c) {
        float wv = wl[c * 64 + o];
        const float4* xp = (const float4*)&xT[c * XS + kb * 8];
        float4 a0 = xp[0], a1 = xp[1];
        acc[0] = fmaf(wv, a0.x, acc[0]); acc[1] = fmaf(wv, a0.y, acc[1]);
        acc[2] = fmaf(wv, a0.z, acc[2]); acc[3] = fmaf(wv, a0.w, acc[3]);
        acc[4] = fmaf(wv, a1.x, acc[4]); acc[5] = fmaf(wv, a1.y, acc[5]);
        acc[6] = fmaf(wv, a1.z, acc[6]); acc[7] = fmaf(wv, a1.w, acc[7]);
    }
    {
        float t = bl[o];
#pragma unroll
        for (int j = 0; j < 8; ++j) {
            float y = acc[j] + t;
            y = y > 0.f ? y : 0.2f * y;
            yA[o * XS + kb * 8 + j] = y;
        }
    }
    __syncthreads();
    for (int i = tid; i < 4096; i += 256) wl[i] = wbuf[4352 + i];
    if (tid < 64) bl[tid] = wbuf[8448 + tid];
    __syncthreads();

    // ---- layer 2: 64 -> 64 ----
#pragma unroll
    for (int j = 0; j < 8; ++j) acc[j] = 0.f;
    for (int c = 0; c < 64; ++c) {
        float wv = wl[c * 64 + o];
        const float4* xp = (const float4*)&yA[c * XS + kb * 8];
        float4 a0 = xp[0], a1 = xp[1];
        acc[0] = fmaf(wv, a0.x, acc[0]); acc[1] = fmaf(wv, a0.y, acc[1]);
        acc[2] = fmaf(wv, a0.z, acc[2]); acc[3] = fmaf(wv, a0.w, acc[3]);
        acc[4] = fmaf(wv, a1.x, acc[4]); acc[5] = fmaf(wv, a1.y, acc[5]);
        acc[6] = fmaf(wv, a1.z, acc[6]); acc[7] = fmaf(wv, a1.w, acc[7]);
    }
    {
        float t = bl[o];
#pragma unroll
        for (int j = 0; j < 8; ++j) {
            float y = acc[j] + t;
            y = y > 0.f ? y : 0.2f * y;
            xT[o * XS + kb * 8 + j] = y;   // y2 into xT (xT reads all done)
        }
    }
    __syncthreads();
    for (int i = tid; i < 8192; i += 256) wl[i] = wbuf[8512 + i];
    if (tid < 128) bl[tid] = wbuf[16704 + tid];
    __syncthreads();

    // ---- layer 3: 64 -> 128, fused max over k ----
    const int o3 = tid & 127, kb3 = tid >> 7;
    float a3[16];
#pragma unroll
    for (int j = 0; j < 16; ++j) a3[j] = 0.f;
    for (int c = 0; c < 64; ++c) {
        float wv = wl[c * 128 + o3];
        const float4* xp = (const float4*)&xT[c * XS + kb3 * 16];
        float4 x0 = xp[0], x1 = xp[1], x2 = xp[2], x3 = xp[3];
        a3[0]  = fmaf(wv, x0.x, a3[0]);  a3[1]  = fmaf(wv, x0.y, a3[1]);
        a3[2]  = fmaf(wv, x0.z, a3[2]);  a3[3]  = fmaf(wv, x0.w, a3[3]);
        a3[4]  = fmaf(wv, x1.x, a3[4]);  a3[5]  = fmaf(wv, x1.y, a3[5]);
        a3[6]  = fmaf(wv, x1.z, a3[6]);  a3[7]  = fmaf(wv, x1.w, a3[7]);
        a3[8]  = fmaf(wv, x2.x, a3[8]);  a3[9]  = fmaf(wv, x2.y, a3[9]);
        a3[10] = fmaf(wv, x2.z, a3[10]); a3[11] = fmaf(wv, x2.w, a3[11]);
        a3[12] = fmaf(wv, x3.x, a3[12]); a3[13] = fmaf(wv, x3.y, a3[13]);
        a3[14] = fmaf(wv, x3.z, a3[14]); a3[15] = fmaf(wv, x3.w, a3[15]);
    }
    {
        float t = bl[o3];
        float m = -3.4e38f;
#pragma unroll
        for (int j = 0; j < 16; ++j) {
            float y = a3[j] + t;
            y = y > 0.f ? y : 0.2f * y;
            m = fmaxf(m, y);
        }
        yA[o3 * 2 + kb3] = m;
    }
    __syncthreads();
    if (tid < 128) {
        float r = fmaxf(yA[tid * 2], yA[tid * 2 + 1]);
        out[((size_t)b * 128 + tid) * NPOINT + q] = r;
    }
}

// ---------------------------------------------------------------------------
extern "C" void kernel_launch(void* const* d_in, const int* in_sizes, int n_in,
                              void* d_out, int out_size, void* d_ws, size_t ws_size,
                              hipStream_t stream) {
    (void)in_sizes; (void)n_in; (void)out_size; (void)ws_size;
    const float* feats  = (const float*)d_in[0];
    const float* points = (const float*)d_in[1];
    const float* w1  = (const float*)d_in[2];
    const float* b1  = (const float*)d_in[3];
    const float* g1  = (const float*)d_in[4];
    const float* bb1 = (const float*)d_in[5];
    const float* m1  = (const float*)d_in[6];
    const float* v1  = (const float*)d_in[7];
    const float* w2  = (const float*)d_in[8];
    const float* b2  = (const float*)d_in[9];
    const float* g2  = (const float*)d_in[10];
    const float* bb2 = (const float*)d_in[11];
    const float* m2  = (const float*)d_in[12];
    const float* v2  = (const float*)d_in[13];
    const float* w3  = (const float*)d_in[14];
    const float* b3  = (const float*)d_in[15];
    const float* g3  = (const float*)d_in[16];
    const float* bb3 = (const float*)d_in[17];
    const float* m3  = (const float*)d_in[18];
    const float* v3  = (const float*)d_in[19];

    float* out = (float*)d_out;
    char*  ws  = (char*)d_ws;
    int*   fidx    = (int*)ws;                           // 8*2048 int = 64 KB
    int*   ballidx = (int*)(ws + 65536);                 // 8*2048*32 int = 2 MB
    float* wbuf    = (float*)(ws + 65536 + 2097152);     // 16832 floats
    float* out_xyz = out + (size_t)NBATCH * 128 * NPOINT;

    hipLaunchKernelGGL(prep_kernel, dim3(66), dim3(256), 0, stream,
                       w1, b1, g1, bb1, m1, v1, w2, b2, g2, bb2, m2, v2,
                       w3, b3, g3, bb3, m3, v3, wbuf);
    hipLaunchKernelGGL(fps_kernel, dim3(NBATCH), dim3(512), 0, stream, points, fidx);
    hipLaunchKernelGGL(bq_kernel, dim3(16384 / 4), dim3(256), 0, stream,
                       points, fidx, ballidx, out_xyz);
    hipLaunchKernelGGL(mlp_kernel, dim3(NBATCH * NPOINT), dim3(256), 0, stream,
                       feats, points, fidx, ballidx, wbuf, out);
}

// Round 9
// 4308.588 us; speedup vs baseline: 1.0933x; 1.0933x over previous
//
#include <hip/hip_runtime.h>
#include <cstdint>
#include <cstddef>

#define NBATCH  8
#define NPTS    8192
#define NFEAT   64
#define NPOINT  2048
#define NSAMPLE 32

// ---------------------------------------------------------------------------
// prep: fold BN into weights (y = dot*s + t), transpose to [c][o]
// ---------------------------------------------------------------------------
__global__ void prep_kernel(const float* __restrict__ w1, const float* __restrict__ b1,
                            const float* __restrict__ g1, const float* __restrict__ bb1,
                            const float* __restrict__ m1, const float* __restrict__ v1,
                            const float* __restrict__ w2, const float* __restrict__ b2,
                            const float* __restrict__ g2, const float* __restrict__ bb2,
                            const float* __restrict__ m2, const float* __restrict__ v2,
                            const float* __restrict__ w3, const float* __restrict__ b3,
                            const float* __restrict__ g3, const float* __restrict__ bb3,
                            const float* __restrict__ m3, const float* __restrict__ v3,
                            float* __restrict__ wbuf) {
    int i = blockIdx.x * 256 + threadIdx.x;
    if (i < 4288) {
        int o = i & 63, c = i >> 6;
        float s = g1[o] / sqrtf(v1[o] + 1e-5f);
        wbuf[i] = w1[o * 67 + c] * s;
    } else if (i < 4352) {
        int o = i - 4288;
        float s = g1[o] / sqrtf(v1[o] + 1e-5f);
        wbuf[i] = (b1[o] - m1[o]) * s + bb1[o];
    } else if (i < 8448) {
        int j = i - 4352; int o = j & 63, c = j >> 6;
        float s = g2[o] / sqrtf(v2[o] + 1e-5f);
        wbuf[i] = w2[o * 64 + c] * s;
    } else if (i < 8512) {
        int o = i - 8448;
        float s = g2[o] / sqrtf(v2[o] + 1e-5f);
        wbuf[i] = (b2[o] - m2[o]) * s + bb2[o];
    } else if (i < 16704) {
        int j = i - 8512; int o = j & 127, c = j >> 7;
        float s = g3[o] / sqrtf(v3[o] + 1e-5f);
        wbuf[i] = w3[o * 64 + c] * s;
    } else if (i < 16832) {
        int o = i - 16704;
        float s = g3[o] / sqrtf(v3[o] + 1e-5f);
        wbuf[i] = (b3[o] - m3[o]) * s + bb3[o];
    }
}

// ---------------------------------------------------------------------------
// FPS, low-pressure brute force.
// 1024 threads (16 waves, 4/SIMD), 8 points/thread register-resident —
// only 32 floats of arrays per thread (~60 live values), far under the
// 128-VGPR budget of launch_bounds(1024,4), so the allocator has no reason
// to demote to scratch (the R7/R8 failure mode). Per iteration:
//   - 8-point exact-IEEE dd update (numpy recipe, bit-exact R1-R8);
//     thread-local argmax on (nd, j).
//   - in-wave argmax via DPP on (v, o) ONLY (R7-validated macro, minimal
//     live state); lane 63 = wave winner.
//   - one barrier; all threads serially scan 16 partials (LDS broadcast);
//     centroid fetched by index from LDS coord tables (staged at setup).
// Tie-break (v>, ==&&idx<) everywhere == numpy argmax.
// ---------------------------------------------------------------------------
template <int CTRL>
__device__ __forceinline__ int dpp_mov(int x) {
    return __builtin_amdgcn_update_dpp(x, x, CTRL, 0xF, 0xF, false);
}

#define DPP_ARGMAX2_STEP(CTRL)                                              \
    do {                                                                    \
        float vv = __int_as_float(dpp_mov<CTRL>(__float_as_int(v)));        \
        int   oo = dpp_mov<CTRL>(o);                                        \
        bool tk = (vv > v) || (vv == v && oo < o);                          \
        v = tk ? vv : v; o = tk ? oo : o;                                   \
    } while (0)

__global__ __launch_bounds__(1024, 4) void fps_kernel(const float* __restrict__ points,
                                                      int* __restrict__ fidx) {
    const int b = blockIdx.x;
    const int tid = threadIdx.x;
    const int lane = tid & 63;
    const int wv = tid >> 6;                 // 16 waves
    const float* __restrict__ pxg = points + (size_t)b * 3 * NPTS;
    const float* __restrict__ pyg = pxg + NPTS;
    const float* __restrict__ pzg = pyg + NPTS;

    __shared__ float lx[NPTS], ly[NPTS], lz[NPTS];   // 96 KB coord tables
    __shared__ float pvs[2][16];
    __shared__ int   pos[2][16];

    float rx[8], ry[8], rz[8], rdd[8];
#pragma unroll
    for (int j = 0; j < 8; ++j) {
        int n = tid + 1024 * j;
        rx[j] = pxg[n]; ry[j] = pyg[n]; rz[j] = pzg[n];
        lx[n] = rx[j];  ly[n] = ry[j];  lz[n] = rz[j];
        rdd[j] = 1e10f;
    }
    if (tid == 0) fidx[b * NPOINT] = 0;
    __syncthreads();
    float cx = lx[0], cy = ly[0], cz = lz[0];   // broadcast LDS reads

    for (int i = 1; i < NPOINT; ++i) {
        // ---- 8-point register update + thread-local argmax ----
        float bv = -1.0f; int bj = 0;
#pragma unroll
        for (int j = 0; j < 8; ++j) {
            float dx = __fsub_rn(rx[j], cx);
            float dy = __fsub_rn(ry[j], cy);
            float dz = __fsub_rn(rz[j], cz);
            float d  = __fadd_rn(__fadd_rn(__fmul_rn(dx, dx), __fmul_rn(dy, dy)),
                                 __fmul_rn(dz, dz));
            float nd = fminf(rdd[j], d);
            rdd[j] = nd;
            bool take = (nd > bv);   // ascending j => ascending n; tie keeps earlier
            bv = take ? nd : bv; bj = take ? j : bj;
        }
        float v = bv; int o = tid + (bj << 10);
        // ---- in-wave argmax via DPP; lane 63 holds the wave winner ----
        DPP_ARGMAX2_STEP(0x111);   // row_shr:1
        DPP_ARGMAX2_STEP(0x112);   // row_shr:2
        DPP_ARGMAX2_STEP(0x114);   // row_shr:4
        DPP_ARGMAX2_STEP(0x118);   // row_shr:8
        DPP_ARGMAX2_STEP(0x142);   // row_bcast15
        DPP_ARGMAX2_STEP(0x143);   // row_bcast31
        const int par = i & 1;
        if (lane == 63) { pvs[par][wv] = v; pos[par][wv] = o; }
        __syncthreads();
        // ---- serial scan of 16 partials (broadcast LDS reads) ----
        float M = pvs[par][0]; int I = pos[par][0];
#pragma unroll
        for (int k = 1; k < 16; ++k) {
            float vk = pvs[par][k]; int ok = pos[par][k];
            bool tk = (vk > M) || (vk == M && ok < I);
            M = tk ? vk : M; I = tk ? ok : I;
        }
        cx = lx[I]; cy = ly[I]; cz = lz[I];   // broadcast indexed fetch
        if (tid == 0) fidx[b * NPOINT + i] = I;
    }
}

// ---------------------------------------------------------------------------
// Ball query: one wave per query. d = (qq+pp) - 2*qp, compare vs 0.04f.
// qp is the K=3 einsum/dot -> ascending FMA chain (verified exact in R1).
// ---------------------------------------------------------------------------
__global__ __launch_bounds__(256) void bq_kernel(const float* __restrict__ points,
                                                 const int* __restrict__ fidx,
                                                 int* __restrict__ ballidx,
                                                 float* __restrict__ out_xyz) {
    const int lane = threadIdx.x & 63;
    const int gw = (blockIdx.x << 2) + (threadIdx.x >> 6);
    const int b = gw >> 11;
    const int q = gw & 2047;
    const float* __restrict__ pxg = points + (size_t)b * 3 * NPTS;
    const float* __restrict__ pyg = pxg + NPTS;
    const float* __restrict__ pzg = pyg + NPTS;
    const int qi = fidx[b * NPOINT + q];
    const float qx = pxg[qi], qy = pyg[qi], qz = pzg[qi];
    const float qq = __fadd_rn(__fadd_rn(__fmul_rn(qx, qx), __fmul_rn(qy, qy)),
                               __fmul_rn(qz, qz));
    int* __restrict__ out = ballidx + ((size_t)(b * NPOINT + q)) * NSAMPLE;
    int have = 0;
    int first = -1;
    for (int base = 0; base < NPTS && have < NSAMPLE; base += 64) {
        const int n = base + lane;
        float x = pxg[n], y = pyg[n], z = pzg[n];
        float pp = __fadd_rn(__fadd_rn(__fmul_rn(x, x), __fmul_rn(y, y)), __fmul_rn(z, z));
        float qp = __builtin_fmaf(qz, z, __builtin_fmaf(qy, y, __fmul_rn(qx, x)));
        float d  = __fsub_rn(__fadd_rn(qq, pp), __fmul_rn(2.0f, qp));
        bool inb = d < 0.04f;   // f32(0.2*0.2) == 0.04f
        unsigned long long mask = __ballot(inb);
        if (mask) {
            if (first < 0) first = base + __ffsll(mask) - 1;
            if (inb) {
                int slot = have + (int)__popcll(mask & ((1ull << lane) - 1ull));
                if (slot < NSAMPLE) out[slot] = n;
            }
            have += (int)__popcll(mask);
        }
    }
    for (int s = have + lane; s < NSAMPLE; s += 64) out[s] = first;
    if (lane == 0) {
        float* o0 = out_xyz + (size_t)b * 3 * NPOINT + q;
        o0[0] = qx; o0[NPOINT] = qy; o0[2 * NPOINT] = qz;
    }
}

// ---------------------------------------------------------------------------
// Fused gather + 3-layer MLP (BN folded) + max-pool. One query per block,
// 256 threads. LDS tiles with stride 36 (float4-aligned, writes only 8-way).
// ---------------------------------------------------------------------------
#define XS 36
__global__ __launch_bounds__(256) void mlp_kernel(const float* __restrict__ feats,
                                                  const float* __restrict__ points,
                                                  const int* __restrict__ fidx,
                                                  const int* __restrict__ ballidx,
                                                  const float* __restrict__ wbuf,
                                                  float* __restrict__ out) {
    __shared__ float xT[67 * XS];   // [c][k], also reused for y2
    __shared__ float yA[64 * XS];   // y1, also reused for final partial max
    __shared__ float wl[8192];      // current layer's folded weights [c][o]
    __shared__ float bl[128];
    __shared__ int   il[32];
    __shared__ float qv[3];
    const int tid = threadIdx.x;
    const int bq = blockIdx.x;
    const int b = bq >> 11, q = bq & 2047;
    const float* __restrict__ pb = points + (size_t)b * 3 * NPTS;

    if (tid < 32) il[tid] = ballidx[((size_t)(b * NPOINT + q)) * NSAMPLE + tid];
    if (tid < 3)  qv[tid] = pb[(size_t)tid * NPTS + fidx[b * NPOINT + q]];
    for (int i = tid; i < 4288; i += 256) wl[i] = wbuf[i];
    if (tid < 64) bl[tid] = wbuf[4288 + tid];
    __syncthreads();

    // build xT: rows 0..2 = grouped_xyz, rows 3..66 = gathered features
    if (tid < 32) {
        int n = il[tid];
        xT[0 * XS + tid] = pb[n] - qv[0];
        xT[1 * XS + tid] = pb[NPTS + n] - qv[1];
        xT[2 * XS + tid] = pb[2 * NPTS + n] - qv[2];
    }
    {
        int k = tid & 31, fg = tid >> 5;
        int n = il[k];
        const float* fb = feats + ((size_t)b * NFEAT + fg * 8) * NPTS + n;
#pragma unroll
        for (int u = 0; u < 8; ++u) xT[(3 + fg * 8 + u) * XS + k] = fb[(size_t)u * NPTS];
    }
    __syncthreads();

    const int o = tid & 63, kb = tid >> 6;
    float acc[8];
    // ---- layer 1: 67 -> 64 ----
#pragma unroll
    for (int j = 0; j < 8; ++j) acc[j] = 0.f;
    for (int c = 0; c < 67; ++c) {
        float wv = wl[c * 64 + o];
        const float4* xp = (const float4*)&xT[c * XS + kb * 8];
        float4 a0 = xp[0], a1 = xp[1];
        acc[0] = fmaf(wv, a0.x, acc[0]); acc[1] = fmaf(wv, a0.y, acc[1]);
        acc[2] = fmaf(wv, a0.z, acc[2]); acc[3] = fmaf(wv, a0.w, acc[3]);
        acc[4] = fmaf(wv, a1.x, acc[4]); acc[5] = fmaf(wv, a1.y, acc[5]);
        acc[6] = fmaf(wv, a1.z, acc[6]); acc[7] = fmaf(wv, a1.w, acc[7]);
    }
    {
        float t = bl[o];
#pragma unroll
        for (int j = 0; j < 8; ++j) {
            float y = acc[j] + t;
            y = y > 0.f ? y : 0.2f * y;
            yA[o * XS + kb * 8 + j] = y;
        }
    }
    __syncthreads();
    for (int i = tid; i < 4096; i += 256) wl[i] = wbuf[4352 + i];
    if (tid < 64) bl[tid] = wbuf[8448 + tid];
    __syncthreads();

    // ---- layer 2: 64 -> 64 ----
#pragma unroll
    for (int j = 0; j < 8; ++j) acc[j] = 0.f;
    for (int c = 0; c < 64; ++c) {
        float wv = wl[c * 64 + o];
        const float4* xp = (const float4*)&yA[c * XS + kb * 8];
        float4 a0 = xp[0], a1 = xp[1];
        acc[0] = fmaf(wv, a0.x, acc[0]); acc[1] = fmaf(wv, a0.y, acc[1]);
        acc[2] = fmaf(wv, a0.z, acc[2]); acc[3] = fmaf(wv, a0.w, acc[3]);
        acc[4] = fmaf(wv, a1.x, acc[4]); acc[5] = fmaf(wv, a1.y, acc[5]);
        acc[6] = fmaf(wv, a1.z, acc[6]); acc[7] = fmaf(wv, a1.w, acc[7]);
    }
    {
        float t = bl[o];
#pragma unroll
        for (int j = 0; j < 8; ++j) {
            float y = acc[j] + t;
            y = y > 0.f ? y : 0.2f * y;
            xT[o * XS + kb * 8 + j] = y;   // y2 into xT (xT reads all done)
        }
    }
    __syncthreads();
    for (int i = tid; i < 8192; i += 256) wl[i] = wbuf[8512 + i];
    if (tid < 128) bl[tid] = wbuf[16704 + tid];
    __syncthreads();

    // ---- layer 3: 64 -> 128, fused max over k ----
    const int o3 = tid & 127, kb3 = tid >> 7;
    float a3[16];
#pragma unroll
    for (int j = 0; j < 16; ++j) a3[j] = 0.f;
    for (int c = 0; c < 64; ++c) {
        float wv = wl[c * 128 + o3];
        const float4* xp = (const float4*)&xT[c * XS + kb3 * 16];
        float4 x0 = xp[0], x1 = xp[1], x2 = xp[2], x3 = xp[3];
        a3[0]  = fmaf(wv, x0.x, a3[0]);  a3[1]  = fmaf(wv, x0.y, a3[1]);
        a3[2]  = fmaf(wv, x0.z, a3[2]);  a3[3]  = fmaf(wv, x0.w, a3[3]);
        a3[4]  = fmaf(wv, x1.x, a3[4]);  a3[5]  = fmaf(wv, x1.y, a3[5]);
        a3[6]  = fmaf(wv, x1.z, a3[6]);  a3[7]  = fmaf(wv, x1.w, a3[7]);
        a3[8]  = fmaf(wv, x2.x, a3[8]);  a3[9]  = fmaf(wv, x2.y, a3[9]);
        a3[10] = fmaf(wv, x2.z, a3[10]); a3[11] = fmaf(wv, x2.w, a3[11]);
        a3[12] = fmaf(wv, x3.x, a3[12]); a3[13] = fmaf(wv, x3.y, a3[13]);
        a3[14] = fmaf(wv, x3.z, a3[14]); a3[15] = fmaf(wv, x3.w, a3[15]);
    }
    {
        float t = bl[o3];
        float m = -3.4e38f;
#pragma unroll
        for (int j = 0; j < 16; ++j) {
            float y = a3[j] + t;
            y = y > 0.f ? y : 0.2f * y;
            m = fmaxf(m, y);
        }
        yA[o3 * 2 + kb3] = m;
    }
    __syncthreads();
    if (tid < 128) {
        float r = fmaxf(yA[tid * 2], yA[tid * 2 + 1]);
        out[((size_t)b * 128 + tid) * NPOINT + q] = r;
    }
}

// ---------------------------------------------------------------------------
extern "C" void kernel_launch(void* const* d_in, const int* in_sizes, int n_in,
                              void* d_out, int out_size, void* d_ws, size_t ws_size,
                              hipStream_t stream) {
    (void)in_sizes; (void)n_in; (void)out_size; (void)ws_size;
    const float* feats  = (const float*)d_in[0];
    const float* points = (const float*)d_in[1];
    const float* w1  = (const float*)d_in[2];
    const float* b1  = (const float*)d_in[3];
    const float* g1  = (const float*)d_in[4];
    const float* bb1 = (const float*)d_in[5];
    const float* m1  = (const float*)d_in[6];
    const float* v1  = (const float*)d_in[7];
    const float* w2  = (const float*)d_in[8];
    const float* b2  = (const float*)d_in[9];
    const float* g2  = (const float*)d_in[10];
    const float* bb2 = (const float*)d_in[11];
    const float* m2  = (const float*)d_in[12];
    const float* v2  = (const float*)d_in[13];
    const float* w3  = (const float*)d_in[14];
    const float* b3  = (const float*)d_in[15];
    const float* g3  = (const float*)d_in[16];
    const float* bb3 = (const float*)d_in[17];
    const float* m3  = (const float*)d_in[18];
    const float* v3  = (const float*)d_in[19];

    float* out = (float*)d_out;
    char*  ws  = (char*)d_ws;
    int*   fidx    = (int*)ws;                           // 8*2048 int = 64 KB
    int*   ballidx = (int*)(ws + 65536);                 // 8*2048*32 int = 2 MB
    float* wbuf    = (float*)(ws + 65536 + 2097152);     // 16832 floats
    float* out_xyz = out + (size_t)NBATCH * 128 * NPOINT;

    hipLaunchKernelGGL(prep_kernel, dim3(66), dim3(256), 0, stream,
                       w1, b1, g1, bb1, m1, v1, w2, b2, g2, bb2, m2, v2,
                       w3, b3, g3, bb3, m3, v3, wbuf);
    hipLaunchKernelGGL(fps_kernel, dim3(NBATCH), dim3(1024), 0, stream, points, fidx);
    hipLaunchKernelGGL(bq_kernel, dim3(16384 / 4), dim3(256), 0, stream,
                       points, fidx, ballidx, out_xyz);
    hipLaunchKernelGGL(mlp_kernel, dim3(NBATCH * NPOINT), dim3(256), 0, stream,
                       feats, points, fidx, ballidx, wbuf, out);
}

// Round 10
// 3223.743 us; speedup vs baseline: 1.4613x; 1.3365x over previous
//
#include <hip/hip_runtime.h>
#include <cstdint>
#include <cstddef>

#define NBATCH  8
#define NPTS    8192
#define NFEAT   64
#define NPOINT  2048
#define NSAMPLE 32

// ---------------------------------------------------------------------------
// prep: fold BN into weights (y = dot*s + t), transpose to [c][o]
// ---------------------------------------------------------------------------
__global__ void prep_kernel(const float* __restrict__ w1, const float* __restrict__ b1,
                            const float* __restrict__ g1, const float* __restrict__ bb1,
                            const float* __restrict__ m1, const float* __restrict__ v1,
                            const float* __restrict__ w2, const float* __restrict__ b2,
                            const float* __restrict__ g2, const float* __restrict__ bb2,
                            const float* __restrict__ m2, const float* __restrict__ v2,
                            const float* __restrict__ w3, const float* __restrict__ b3,
                            const float* __restrict__ g3, const float* __restrict__ bb3,
                            const float* __restrict__ m3, const float* __restrict__ v3,
                            float* __restrict__ wbuf) {
    int i = blockIdx.x * 256 + threadIdx.x;
    if (i < 4288) {
        int o = i & 63, c = i >> 6;
        float s = g1[o] / sqrtf(v1[o] + 1e-5f);
        wbuf[i] = w1[o * 67 + c] * s;
    } else if (i < 4352) {
        int o = i - 4288;
        float s = g1[o] / sqrtf(v1[o] + 1e-5f);
        wbuf[i] = (b1[o] - m1[o]) * s + bb1[o];
    } else if (i < 8448) {
        int j = i - 4352; int o = j & 63, c = j >> 6;
        float s = g2[o] / sqrtf(v2[o] + 1e-5f);
        wbuf[i] = w2[o * 64 + c] * s;
    } else if (i < 8512) {
        int o = i - 8448;
        float s = g2[o] / sqrtf(v2[o] + 1e-5f);
        wbuf[i] = (b2[o] - m2[o]) * s + bb2[o];
    } else if (i < 16704) {
        int j = i - 8512; int o = j & 127, c = j >> 7;
        float s = g3[o] / sqrtf(v3[o] + 1e-5f);
        wbuf[i] = w3[o * 64 + c] * s;
    } else if (i < 16832) {
        int o = i - 16704;
        float s = g3[o] / sqrtf(v3[o] + 1e-5f);
        wbuf[i] = (b3[o] - m3[o]) * s + bb3[o];
    }
}

// ---------------------------------------------------------------------------
// FPS — literal R3 kernel (the only register-resident variant: VGPR=88,
// no scratch, 2760 us measured). 512 threads, 16 pts/thread in registers,
// LDS coord tables for the broadcast centroid fetch, shfl-butterfly reduce.
// Exact IEEE f32 recipe, tie-break -> smallest index (numpy argmax).
// ---------------------------------------------------------------------------
__global__ __launch_bounds__(512, 2) void fps_kernel(const float* __restrict__ points,
                                                     int* __restrict__ fidx) {
    const int b = blockIdx.x;
    const int tid = threadIdx.x;
    const int lane = tid & 63;
    const float* __restrict__ pxg = points + (size_t)b * 3 * NPTS;
    const float* __restrict__ pyg = pxg + NPTS;
    const float* __restrict__ pzg = pyg + NPTS;

    __shared__ float lx[NPTS];     // 32 KB
    __shared__ float ly[NPTS];     // 32 KB
    __shared__ float lz[NPTS];     // 32 KB
    __shared__ float pv[2][8];
    __shared__ int   pi[2][8];

    float px[16], py[16], pz[16], dd[16];
#pragma unroll
    for (int j = 0; j < 16; ++j) {
        int n = tid + 512 * j;
        px[j] = pxg[n]; py[j] = pyg[n]; pz[j] = pzg[n];
        lx[n] = px[j];  ly[n] = py[j];  lz[n] = pz[j];
        dd[j] = 1e10f;
    }
    if (tid == 0) fidx[b * NPOINT + 0] = 0;
    __syncthreads();
    int w = 0;
    for (int i = 1; i < NPOINT; ++i) {
        // broadcast read of current centroid from LDS (same addr all lanes)
        const float cx = lx[w], cy = ly[w], cz = lz[w];
        float bestd = -1.0f; int besti = 0;
#pragma unroll
        for (int j = 0; j < 16; ++j) {
            float dx = __fsub_rn(px[j], cx);
            float dy = __fsub_rn(py[j], cy);
            float dz = __fsub_rn(pz[j], cz);
            float d  = __fadd_rn(__fadd_rn(__fmul_rn(dx, dx), __fmul_rn(dy, dy)),
                                 __fmul_rn(dz, dz));
            float nd = fminf(dd[j], d);
            dd[j] = nd;
            bool better = (nd > bestd);   // strict > keeps smaller idx on tie
            bestd = better ? nd : bestd;
            besti = better ? (tid + 512 * j) : besti;
        }
        // wave-level argmax reduce (max dist, tie -> min idx)
#pragma unroll
        for (int off = 32; off >= 1; off >>= 1) {
            float od = __shfl_down(bestd, off);
            int   oi = __shfl_down(besti, off);
            bool take = (od > bestd) || (od == bestd && oi < besti);
            bestd = take ? od : bestd;
            besti = take ? oi : besti;
        }
        const int par = i & 1;  // double-buffered partials -> single barrier/iter
        if (lane == 0) { pv[par][tid >> 6] = bestd; pi[par][tid >> 6] = besti; }
        __syncthreads();
        // every wave redundantly reduces the 8 partials (no broadcast barrier)
        float fd = (lane < 8) ? pv[par][lane] : -1.0f;
        int   fi = (lane < 8) ? pi[par][lane] : 0x7fffffff;
#pragma unroll
        for (int off = 4; off >= 1; off >>= 1) {
            float od = __shfl_down(fd, off);
            int   oi = __shfl_down(fi, off);
            bool take = (od > fd) || (od == fd && oi < fi);
            fd = take ? od : fd;
            fi = take ? oi : fi;
        }
        w = __shfl(fi, 0);
        if (tid == 0) fidx[b * NPOINT + i] = w;
    }
}

// ---------------------------------------------------------------------------
// Ball query: one wave per query. d = (qq+pp) - 2*qp, compare vs 0.04f.
// qp is the K=3 einsum/dot -> ascending FMA chain (verified exact in R1).
// ---------------------------------------------------------------------------
__global__ __launch_bounds__(256) void bq_kernel(const float* __restrict__ points,
                                                 const int* __restrict__ fidx,
                                                 int* __restrict__ ballidx,
                                                 float* __restrict__ out_xyz) {
    const int lane = threadIdx.x & 63;
    const int gw = (blockIdx.x << 2) + (threadIdx.x >> 6);
    const int b = gw >> 11;
    const int q = gw & 2047;
    const float* __restrict__ pxg = points + (size_t)b * 3 * NPTS;
    const float* __restrict__ pyg = pxg + NPTS;
    const float* __restrict__ pzg = pyg + NPTS;
    const int qi = fidx[b * NPOINT + q];
    const float qx = pxg[qi], qy = pyg[qi], qz = pzg[qi];
    const float qq = __fadd_rn(__fadd_rn(__fmul_rn(qx, qx), __fmul_rn(qy, qy)),
                               __fmul_rn(qz, qz));
    int* __restrict__ out = ballidx + ((size_t)(b * NPOINT + q)) * NSAMPLE;
    int have = 0;
    int first = -1;
    for (int base = 0; base < NPTS && have < NSAMPLE; base += 64) {
        const int n = base + lane;
        float x = pxg[n], y = pyg[n], z = pzg[n];
        float pp = __fadd_rn(__fadd_rn(__fmul_rn(x, x), __fmul_rn(y, y)), __fmul_rn(z, z));
        float qp = __builtin_fmaf(qz, z, __builtin_fmaf(qy, y, __fmul_rn(qx, x)));
        float d  = __fsub_rn(__fadd_rn(qq, pp), __fmul_rn(2.0f, qp));
        bool inb = d < 0.04f;   // f32(0.2*0.2) == 0.04f
        unsigned long long mask = __ballot(inb);
        if (mask) {
            if (first < 0) first = base + __ffsll(mask) - 1;
            if (inb) {
                int slot = have + (int)__popcll(mask & ((1ull << lane) - 1ull));
                if (slot < NSAMPLE) out[slot] = n;
            }
            have += (int)__popcll(mask);
        }
    }
    for (int s = have + lane; s < NSAMPLE; s += 64) out[s] = first;
    if (lane == 0) {
        float* o0 = out_xyz + (size_t)b * 3 * NPOINT + q;
        o0[0] = qx; o0[NPOINT] = qy; o0[2 * NPOINT] = qz;
    }
}

// ---------------------------------------------------------------------------
// Fused gather + 3-layer MLP + max-pool, TWO queries per block (k = 64).
// Halves weight-staging traffic and block count vs 1-query version; layer-3's
// kb3 groups each cover exactly one query's 32 samples, so the max-pool
// finishes in-thread and stores directly to global (no final reduction).
// Same FMA order per output as before -> bit-identical results.
// ---------------------------------------------------------------------------
#define XS2 68   // 64 + 4 pad (16B-aligned rows, 8-way-max write conflicts)
__global__ __launch_bounds__(256) void mlp_kernel(const float* __restrict__ feats,
                                                  const float* __restrict__ points,
                                                  const int* __restrict__ fidx,
                                                  const int* __restrict__ ballidx,
                                                  const float* __restrict__ wbuf,
                                                  float* __restrict__ out) {
    __shared__ __align__(16) float xT[67 * XS2];   // [c][k], reused for y2
    __shared__ __align__(16) float yA[64 * XS2];   // y1
    __shared__ __align__(16) float wl[8192];       // current layer weights [c][o]
    __shared__ float bl[128];
    __shared__ int   il[64];
    __shared__ float qv[6];
    const int tid = threadIdx.x;
    const int blk = blockIdx.x;
    const int b = blk >> 10;            // 1024 query-pairs per batch
    const int q0 = (blk & 1023) * 2;
    const float* __restrict__ pb = points + (size_t)b * 3 * NPTS;
    const float4* __restrict__ wb4 = (const float4*)wbuf;

    if (tid < 64)
        il[tid] = ballidx[((size_t)(b * NPOINT + q0 + (tid >> 5))) * NSAMPLE + (tid & 31)];
    if (tid < 6) {
        int qq_ = tid / 3, dim = tid % 3;
        qv[tid] = pb[(size_t)dim * NPTS + fidx[b * NPOINT + q0 + qq_]];
    }
    // stage layer-1 weights (4288 floats = 1072 float4)
    for (int i = tid; i < 1072; i += 256) ((float4*)wl)[i] = wb4[i];
    if (tid < 64) bl[tid] = wbuf[4288 + tid];
    __syncthreads();

    // build xT: rows 0..2 = grouped_xyz, rows 3..66 = gathered features
    if (tid < 64) {
        int n = il[tid], qsel = tid >> 5;
        xT[0 * XS2 + tid] = pb[n] - qv[qsel * 3 + 0];
        xT[1 * XS2 + tid] = pb[NPTS + n] - qv[qsel * 3 + 1];
        xT[2 * XS2 + tid] = pb[2 * NPTS + n] - qv[qsel * 3 + 2];
    }
    {
        int k = tid & 63, fg = tid >> 6;          // 4 groups x 16 feature rows
        int n = il[k];
        const float* fb = feats + ((size_t)b * NFEAT + fg * 16) * NPTS + n;
#pragma unroll
        for (int u = 0; u < 16; ++u) xT[(3 + fg * 16 + u) * XS2 + k] = fb[(size_t)u * NPTS];
    }
    __syncthreads();

    const int o = tid & 63, w = tid >> 6;   // wave w owns samples [w*16, w*16+16)
    float acc[16];
    // ---- layer 1: 67 -> 64 ----
#pragma unroll
    for (int j = 0; j < 16; ++j) acc[j] = 0.f;
    for (int c = 0; c < 67; ++c) {
        float wv = wl[c * 64 + o];
        const float4* xp = (const float4*)&xT[c * XS2 + w * 16];
        float4 a0 = xp[0], a1 = xp[1], a2 = xp[2], a3v = xp[3];
        acc[0]  = fmaf(wv, a0.x, acc[0]);  acc[1]  = fmaf(wv, a0.y, acc[1]);
        acc[2]  = fmaf(wv, a0.z, acc[2]);  acc[3]  = fmaf(wv, a0.w, acc[3]);
        acc[4]  = fmaf(wv, a1.x, acc[4]);  acc[5]  = fmaf(wv, a1.y, acc[5]);
        acc[6]  = fmaf(wv, a1.z, acc[6]);  acc[7]  = fmaf(wv, a1.w, acc[7]);
        acc[8]  = fmaf(wv, a2.x, acc[8]);  acc[9]  = fmaf(wv, a2.y, acc[9]);
        acc[10] = fmaf(wv, a2.z, acc[10]); acc[11] = fmaf(wv, a2.w, acc[11]);
        acc[12] = fmaf(wv, a3v.x, acc[12]); acc[13] = fmaf(wv, a3v.y, acc[13]);
        acc[14] = fmaf(wv, a3v.z, acc[14]); acc[15] = fmaf(wv, a3v.w, acc[15]);
    }
    {
        float t = bl[o];
#pragma unroll
        for (int j = 0; j < 16; ++j) {
            float y = acc[j] + t;
            y = y > 0.f ? y : 0.2f * y;
            yA[o * XS2 + w * 16 + j] = y;
        }
    }
    __syncthreads();
    for (int i = tid; i < 1024; i += 256) ((float4*)wl)[i] = wb4[1088 + i];
    if (tid < 64) bl[tid] = wbuf[8448 + tid];
    __syncthreads();

    // ---- layer 2: 64 -> 64 ----
#pragma unroll
    for (int j = 0; j < 16; ++j) acc[j] = 0.f;
    for (int c = 0; c < 64; ++c) {
        float wv = wl[c * 64 + o];
        const float4* xp = (const float4*)&yA[c * XS2 + w * 16];
        float4 a0 = xp[0], a1 = xp[1], a2 = xp[2], a3v = xp[3];
        acc[0]  = fmaf(wv, a0.x, acc[0]);  acc[1]  = fmaf(wv, a0.y, acc[1]);
        acc[2]  = fmaf(wv, a0.z, acc[2]);  acc[3]  = fmaf(wv, a0.w, acc[3]);
        acc[4]  = fmaf(wv, a1.x, acc[4]);  acc[5]  = fmaf(wv, a1.y, acc[5]);
        acc[6]  = fmaf(wv, a1.z, acc[6]);  acc[7]  = fmaf(wv, a1.w, acc[7]);
        acc[8]  = fmaf(wv, a2.x, acc[8]);  acc[9]  = fmaf(wv, a2.y, acc[9]);
        acc[10] = fmaf(wv, a2.z, acc[10]); acc[11] = fmaf(wv, a2.w, acc[11]);
        acc[12] = fmaf(wv, a3v.x, acc[12]); acc[13] = fmaf(wv, a3v.y, acc[13]);
        acc[14] = fmaf(wv, a3v.z, acc[14]); acc[15] = fmaf(wv, a3v.w, acc[15]);
    }
    {
        float t = bl[o];
#pragma unroll
        for (int j = 0; j < 16; ++j) {
            float y = acc[j] + t;
            y = y > 0.f ? y : 0.2f * y;
            xT[o * XS2 + w * 16 + j] = y;   // y2 into xT (xT reads all done)
        }
    }
    __syncthreads();
    for (int i = tid; i < 2048; i += 256) ((float4*)wl)[i] = wb4[2128 + i];
    if (tid < 128) bl[tid] = wbuf[16704 + tid];
    __syncthreads();

    // ---- layer 3: 64 -> 128, max over this thread's query (32 samples) ----
    const int o3 = tid & 127, kb3 = tid >> 7;   // kb3 = query select
    float a3[32];
#pragma unroll
    for (int j = 0; j < 32; ++j) a3[j] = 0.f;
    for (int c = 0; c < 64; ++c) {
        float wv = wl[c * 128 + o3];
        const float4* xp = (const float4*)&xT[c * XS2 + kb3 * 32];
#pragma unroll
        for (int g = 0; g < 8; ++g) {
            float4 x = xp[g];
            a3[g * 4 + 0] = fmaf(wv, x.x, a3[g * 4 + 0]);
            a3[g * 4 + 1] = fmaf(wv, x.y, a3[g * 4 + 1]);
            a3[g * 4 + 2] = fmaf(wv, x.z, a3[g * 4 + 2]);
            a3[g * 4 + 3] = fmaf(wv, x.w, a3[g * 4 + 3]);
        }
    }
    {
        float t = bl[o3];
        float m = -3.4e38f;
#pragma unroll
        for (int j = 0; j < 32; ++j) {
            float y = a3[j] + t;
            y = y > 0.f ? y : 0.2f * y;
            m = fmaxf(m, y);
        }
        out[((size_t)b * 128 + o3) * NPOINT + q0 + kb3] = m;
    }
}

// ---------------------------------------------------------------------------
extern "C" void kernel_launch(void* const* d_in, const int* in_sizes, int n_in,
                              void* d_out, int out_size, void* d_ws, size_t ws_size,
                              hipStream_t stream) {
    (void)in_sizes; (void)n_in; (void)out_size; (void)ws_size;
    const float* feats  = (const float*)d_in[0];
    const float* points = (const float*)d_in[1];
    const float* w1  = (const float*)d_in[2];
    const float* b1  = (const float*)d_in[3];
    const float* g1  = (const float*)d_in[4];
    const float* bb1 = (const float*)d_in[5];
    const float* m1  = (const float*)d_in[6];
    const float* v1  = (const float*)d_in[7];
    const float* w2  = (const float*)d_in[8];
    const float* b2  = (const float*)d_in[9];
    const float* g2  = (const float*)d_in[10];
    const float* bb2 = (const float*)d_in[11];
    const float* m2  = (const float*)d_in[12];
    const float* v2  = (const float*)d_in[13];
    const float* w3  = (const float*)d_in[14];
    const float* b3  = (const float*)d_in[15];
    const float* g3  = (const float*)d_in[16];
    const float* bb3 = (const float*)d_in[17];
    const float* m3  = (const float*)d_in[18];
    const float* v3  = (const float*)d_in[19];

    float* out = (float*)d_out;
    char*  ws  = (char*)d_ws;
    int*   fidx    = (int*)ws;                           // 8*2048 int = 64 KB
    int*   ballidx = (int*)(ws + 65536);                 // 8*2048*32 int = 2 MB
    float* wbuf    = (float*)(ws + 65536 + 2097152);     // 16832 floats
    float* out_xyz = out + (size_t)NBATCH * 128 * NPOINT;

    hipLaunchKernelGGL(prep_kernel, dim3(66), dim3(256), 0, stream,
                       w1, b1, g1, bb1, m1, v1, w2, b2, g2, bb2, m2, v2,
                       w3, b3, g3, bb3, m3, v3, wbuf);
    hipLaunchKernelGGL(fps_kernel, dim3(NBATCH), dim3(512), 0, stream, points, fidx);
    hipLaunchKernelGGL(bq_kernel, dim3(16384 / 4), dim3(256), 0, stream,
                       points, fidx, ballidx, out_xyz);
    hipLaunchKernelGGL(mlp_kernel, dim3(NBATCH * 1024), dim3(256), 0, stream,
                       feats, points, fidx, ballidx, wbuf, out);
}